// Round 6
// baseline (1000.430 us; speedup 1.0000x reference)
//
#include <hip/hip_runtime.h>

#define EPS 1e-12f
#define NSCAN 256   // scan blocks/threads

typedef int v2i __attribute__((ext_vector_type(2)));

// ---------------------------------------------------------------------------
// Pipeline:
//   memset cursor -> count (int4-vectorized) -> scan(3) -> fill (int4-vec,
//   atomicSub) -> repack verts to float4-padded -> gather.
// Gather confinement: xcd = blockIdx&7 (round-robin block->XCD dispatch);
//   each XCD handles batches {bl*8+xcd}, bl slowest -> one batch in flight
//   per XCD at FULL occupancy; its 3.2 MB float4 vertex array lives in that
//   XCD's 4 MB L2. CSR/output use nontemporal accesses (evict-first).
// CSR entry at corner v of face (i0,i1,i2) stores the other two indices (a,b)
// cyclically; (A-v)x(B-v) == reference cross(v2-v1, v0-v1) at every corner.
// ---------------------------------------------------------------------------

__global__ void count_kernel(const int4* __restrict__ faces4, int* __restrict__ counts,
                             int F4, int F) {
    int t = blockIdx.x * blockDim.x + threadIdx.x;
    if (t >= F4) return;
    int4 a = faces4[3 * t], b = faces4[3 * t + 1], c = faces4[3 * t + 2];
    int w[12] = {a.x, a.y, a.z, a.w, b.x, b.y, b.z, b.w, c.x, c.y, c.z, c.w};
    int base = 4 * t;
#pragma unroll
    for (int i = 0; i < 12; i++) {
        if (base + i / 3 < F) atomicAdd(&counts[w[i]], 1);
    }
}

__global__ __launch_bounds__(NSCAN) void scan_partials(const int* __restrict__ counts,
                                                       int* __restrict__ partials,
                                                       int V, int chunk) {
    int b = blockIdx.x, t = threadIdx.x;
    int bstart = b * chunk;
    int bend = min(bstart + chunk, V);
    int s = 0;
    for (int i = bstart + t; i < bend; i += NSCAN) s += counts[i];
    __shared__ int red[NSCAN];
    red[t] = s;
    __syncthreads();
    for (int o = NSCAN / 2; o > 0; o >>= 1) {
        if (t < o) red[t] += red[t + o];
        __syncthreads();
    }
    if (t == 0) partials[b] = red[0];
}

__global__ __launch_bounds__(NSCAN) void scan_top(int* __restrict__ partials) {
    __shared__ int s[NSCAN];
    int t = threadIdx.x;
    int v = partials[t];
    s[t] = v;
    __syncthreads();
    for (int o = 1; o < NSCAN; o <<= 1) {
        int u = (t >= o) ? s[t - o] : 0;
        __syncthreads();
        s[t] += u;
        __syncthreads();
    }
    partials[t] = s[t] - v;  // exclusive
}

__global__ __launch_bounds__(NSCAN) void scan_final(const int* __restrict__ counts,
                                                    const int* __restrict__ partials,
                                                    int* __restrict__ offsets,
                                                    int V, int chunk) {
    int b = blockIdx.x, t = threadIdx.x;
    int bstart = b * chunk;
    int bend = min(bstart + chunk, V);
    int sc = (chunk + NSCAN - 1) / NSCAN;
    int tstart = bstart + t * sc;
    int tend = min(tstart + sc, bend);
    int c[8];
    int n = 0, tsum = 0;
    for (int i = tstart; i < tend; i++) {
        int cv = counts[i];
        c[n++] = cv;
        tsum += cv;
    }
    __shared__ int s[NSCAN];
    s[t] = tsum;
    __syncthreads();
    for (int o = 1; o < NSCAN; o <<= 1) {
        int u = (t >= o) ? s[t - o] : 0;
        __syncthreads();
        s[t] += u;
        __syncthreads();
    }
    int run = partials[b] + s[t] - tsum;
    n = 0;
    for (int i = tstart; i < tend; i++) {
        offsets[i] = run;
        run += c[n++];
    }
    if (bend == V && tend == V) offsets[V] = run;
}

__global__ void fill_kernel(const int4* __restrict__ faces4,
                            const int* __restrict__ offsets,
                            int* __restrict__ cursor,
                            v2i* __restrict__ csr, int F4, int F) {
    int t = blockIdx.x * blockDim.x + threadIdx.x;
    if (t >= F4) return;
    int4 a = faces4[3 * t], b = faces4[3 * t + 1], c = faces4[3 * t + 2];
    int w[12] = {a.x, a.y, a.z, a.w, b.x, b.y, b.z, b.w, c.x, c.y, c.z, c.w};
    int base = 4 * t;
#pragma unroll
    for (int f = 0; f < 4; f++) {
        if (base + f >= F) break;
        int i0 = w[3 * f], i1 = w[3 * f + 1], i2 = w[3 * f + 2];
        int vs[3] = {i0, i1, i2};
        int as[3] = {i1, i2, i0};
        int bs[3] = {i2, i0, i1};
#pragma unroll
        for (int cc = 0; cc < 3; cc++) {
            int v = vs[cc];
            int old = atomicSub(&cursor[v], 1);
            int pos = offsets[v] + old - 1;
            v2i e; e.x = as[cc]; e.y = bs[cc];
            csr[pos] = e;
        }
    }
}

// repack: float3 verts -> float4-padded (one dwordx4 per random gather later)
__global__ void repack_kernel(const float4* __restrict__ in4, float4* __restrict__ out4,
                              int ngroups) {
    int j = blockIdx.x * blockDim.x + threadIdx.x;
    if (j >= ngroups) return;
    float4 a = in4[3 * j], b = in4[3 * j + 1], c = in4[3 * j + 2];
    out4[4 * j + 0] = make_float4(a.x, a.y, a.z, 0.f);
    out4[4 * j + 1] = make_float4(a.w, b.x, b.y, 0.f);
    out4[4 * j + 2] = make_float4(b.z, b.w, c.x, 0.f);
    out4[4 * j + 3] = make_float4(c.y, c.z, c.w, 0.f);
}

// gather: per-XCD sequential batch drain at full occupancy.
__global__ __launch_bounds__(256) void gather_kernel(const float4* __restrict__ vert4,
                                                     const int* __restrict__ offsets,
                                                     const v2i* __restrict__ csr,
                                                     float* __restrict__ out,
                                                     int V, int B, int vblocks) {
    int i = blockIdx.x;
    int xcd = i & 7;
    int j = i >> 3;
    int bl = j / vblocks;        // batch_local (slowest within XCD)
    int xb = j - bl * vblocks;   // vertex block
    int batch = bl * 8 + xcd;
    int v = xb * 256 + threadIdx.x;
    if (v >= V || batch >= B) return;

    const float4* vb = vert4 + (size_t)batch * V;
    float4 P = vb[v];

    int s = offsets[v];
    int e = offsets[v + 1];
    float ax = 0.f, ay = 0.f, az = 0.f;
    for (int k = s; k < e; k++) {
        v2i p = __builtin_nontemporal_load(&csr[k]);
        float4 A = vb[p.x];
        float4 Bq = vb[p.y];
        float aX = A.x - P.x, aY = A.y - P.y, aZ = A.z - P.z;
        float bX = Bq.x - P.x, bY = Bq.y - P.y, bZ = Bq.z - P.z;
        ax += aY * bZ - aZ * bY;
        ay += aZ * bX - aX * bZ;
        az += aX * bY - aY * bX;
    }
    float sc = rsqrtf(fmaxf(ax * ax + ay * ay + az * az, EPS));
    size_t o = ((size_t)batch * V + v) * 3;
    __builtin_nontemporal_store(ax * sc, &out[o + 0]);
    __builtin_nontemporal_store(ay * sc, &out[o + 1]);
    __builtin_nontemporal_store(az * sc, &out[o + 2]);
}

// fallback gather (no repack) if ws too small for vert4
__global__ __launch_bounds__(256) void gather_kernel_f3(const float* __restrict__ verts,
                                                        const int* __restrict__ offsets,
                                                        const v2i* __restrict__ csr,
                                                        float* __restrict__ out,
                                                        int V, int B, int vblocks) {
    int i = blockIdx.x;
    int xcd = i & 7;
    int j = i >> 3;
    int bl = j / vblocks;
    int xb = j - bl * vblocks;
    int batch = bl * 8 + xcd;
    int v = xb * 256 + threadIdx.x;
    if (v >= V || batch >= B) return;
    const float* vb = verts + (size_t)batch * V * 3;
    float vx = vb[3 * v + 0], vy = vb[3 * v + 1], vz = vb[3 * v + 2];
    int s = offsets[v];
    int e = offsets[v + 1];
    float ax = 0.f, ay = 0.f, az = 0.f;
    for (int k = s; k < e; k++) {
        v2i p = __builtin_nontemporal_load(&csr[k]);
        const float* A = vb + 3 * (size_t)p.x;
        const float* Bv = vb + 3 * (size_t)p.y;
        float aX = A[0] - vx, aY = A[1] - vy, aZ = A[2] - vz;
        float bX = Bv[0] - vx, bY = Bv[1] - vy, bZ = Bv[2] - vz;
        ax += aY * bZ - aZ * bY;
        ay += aZ * bX - aX * bZ;
        az += aX * bY - aY * bX;
    }
    float sc = rsqrtf(fmaxf(ax * ax + ay * ay + az * az, EPS));
    size_t o = ((size_t)batch * V + v) * 3;
    __builtin_nontemporal_store(ax * sc, &out[o + 0]);
    __builtin_nontemporal_store(ay * sc, &out[o + 1]);
    __builtin_nontemporal_store(az * sc, &out[o + 2]);
}

extern "C" void kernel_launch(void* const* d_in, const int* in_sizes, int n_in,
                              void* d_out, int out_size, void* d_ws, size_t ws_size,
                              hipStream_t stream) {
    const float* verts = (const float*)d_in[0];
    const int* faces = (const int*)d_in[1];
    float* out = (float*)d_out;

    const int V = 200000;
    const int F = in_sizes[1] / 3;           // 400000
    const int B = in_sizes[0] / (3 * V);     // 32
    const int F4 = (F + 3) / 4;

    // ws layout: offsets[V+1] | cursor[V] | partials[NSCAN] | csr[3F] int2 | vert4[B*V] float4
    char* wp = (char*)d_ws;
    int* offsets = (int*)wp;                 wp += (size_t)(V + 1) * 4;
    int* cursor = (int*)wp;                  wp += (size_t)V * 4;
    int* partials = (int*)wp;                wp += (size_t)NSCAN * 4;
    v2i* csr = (v2i*)wp;                     wp += (size_t)(3 * F) * 8;
    size_t used = (size_t)(wp - (char*)d_ws);
    used = (used + 15) & ~(size_t)15;
    float4* vert4 = (float4*)((char*)d_ws + used);
    size_t need_vert4 = used + (size_t)B * V * 16;

    const int chunk = (V + NSCAN - 1) / NSCAN;  // 782
    const int vblocks = (V + 255) / 256;        // 782
    const int nbx = (B + 7) / 8;                // batches per XCD = 4

    hipMemsetAsync(cursor, 0, (size_t)V * 4, stream);
    count_kernel<<<(F4 + 255) / 256, 256, 0, stream>>>((const int4*)faces, cursor, F4, F);
    scan_partials<<<NSCAN, NSCAN, 0, stream>>>(cursor, partials, V, chunk);
    scan_top<<<1, NSCAN, 0, stream>>>(partials);
    scan_final<<<NSCAN, NSCAN, 0, stream>>>(cursor, partials, offsets, V, chunk);
    fill_kernel<<<(F4 + 255) / 256, 256, 0, stream>>>((const int4*)faces, offsets, cursor,
                                                      csr, F4, F);

    int nblk = 8 * nbx * vblocks;  // 25024
    if (ws_size >= need_vert4) {
        int ngroups = (B * V) / 4;  // 1.6M (B*V divisible by 4)
        repack_kernel<<<(ngroups + 255) / 256, 256, 0, stream>>>((const float4*)verts,
                                                                 vert4, ngroups);
        gather_kernel<<<nblk, 256, 0, stream>>>(vert4, offsets, csr, out, V, B, vblocks);
    } else {
        gather_kernel_f3<<<nblk, 256, 0, stream>>>(verts, offsets, csr, out, V, B, vblocks);
    }
}